// Round 1
// baseline (207.413 us; speedup 1.0000x reference)
//
#include <hip/hip_runtime.h>
#include <math.h>

#define T_TOTAL 262144
#define HIDN 20
#define IND 9

// ---- v2 scan geometry: 4096 blocks -> 16 blocks/CU -> 4 waves/SIMD
#define CHUNK 64
#define WARM 32
#define NBLK (T_TOTAL / CHUNK)          // 4096

// xg workspace: [T][20] float4 (gates i,f,g,o per unit), bias b1 folded in
#define XG_BYTES ((size_t)T_TOTAL * 4 * HIDN * sizeof(float))   // 83.9 MB

typedef float float4v __attribute__((ext_vector_type(4)));

__device__ __forceinline__ float fexp(float x) {
    return __builtin_amdgcn_exp2f(x * 1.44269504088896340736f);
}
__device__ __forceinline__ float sigf(float x) {
    return __builtin_amdgcn_rcpf(1.0f + fexp(-x));
}
__device__ __forceinline__ float tanhfst(float x) {
    return 1.0f - 2.0f * __builtin_amdgcn_rcpf(1.0f + fexp(2.0f * x));
}
__device__ __forceinline__ float hsum4(float4v a) {
    return (a.x + a.y) + (a.z + a.w);
}

// ============================================================================
// Kernel 1: xg[t][k] = b1 + W_ih1 . x[t]  (recurrence-independent, like the
// JAX reference's einsum precompute). Write-BW bound (~84MB). Coalesced
// float4 stores; weights staged in LDS.
// ============================================================================
__global__ __launch_bounds__(256)
void xproj(const float* __restrict__ x, const float* __restrict__ w_ih1,
           const float* __restrict__ b1, float4v* __restrict__ xg)
{
    __shared__ float wsm[4 * HIDN * IND + 4 * HIDN];   // 720 w + 80 b
    const int tid = threadIdx.x;
    for (int i = tid; i < 4 * HIDN * IND; i += 256) wsm[i] = w_ih1[i];
    for (int i = tid; i < 4 * HIDN; i += 256) wsm[4 * HIDN * IND + i] = b1[i];
    __syncthreads();

    const unsigned idx = blockIdx.x * 256 + tid;   // = t*20 + k, grid covers T*20 exactly
    const unsigned t = idx / HIDN;
    const int k = (int)(idx - t * HIDN);
    const float* xr = x + (size_t)t * IND;
    float xv[IND];
#pragma unroll
    for (int d = 0; d < IND; ++d) xv[d] = xr[d];   // 20 lanes share each t -> L1 hits

    float4v r;
#pragma unroll
    for (int q = 0; q < 4; ++q) {
        const float* wr = &wsm[(q * HIDN + k) * IND];
        float acc = wsm[4 * HIDN * IND + q * HIDN + k];
#pragma unroll
        for (int d = 0; d < IND; ++d) acc = fmaf(wr[d], xv[d], acc);
        r[q] = acc;
    }
    xg[idx] = r;    // coalesced 16B/lane
}

// ============================================================================
// Kernel 2: recurrent scan. Lanes 0-19: layer1 unit k (h-dot only, xg adds
// the input projection). Lanes 20-39: layer2 W_ih2 half (state owner).
// Lanes 40-59: layer2 W_hh2 half. Lanes 60-63 idle.
// Per-lane weights: uniform 20 float4 + bias -> fits registers (no spill),
// unlike the old 120-float footprint at VGPR_Count=88.
// __launch_bounds__(64,4): pin VGPR<=128 so 16 blocks/CU co-reside.
// ============================================================================
#define DECLW2(q) float4v wv##q##0, wv##q##1, wv##q##2, wv##q##3, wv##q##4; float bq##q;
#define LOADW2(q) { \
    const float4v* wr = (const float4v*)(wbase + ((q) * HIDN + krow) * HIDN); \
    wv##q##0 = scale * wr[0]; wv##q##1 = scale * wr[1]; wv##q##2 = scale * wr[2]; \
    wv##q##3 = scale * wr[3]; wv##q##4 = scale * wr[4]; \
    bq##q = (grp == 1) ? b2[(q) * HIDN + k] : 0.0f; \
}

#define XGIDX(t) (((unsigned)(((t) < T_TOTAL) ? (t) : (T_TOTAL - 1))) * HIDN + krow)

__global__ __launch_bounds__(64, 4)
void lstm_scan2(const float4v* __restrict__ xg,
                const float* __restrict__ w_hh1,
                const float* __restrict__ w_ih2, const float* __restrict__ w_hh2,
                const float* __restrict__ b2,
                const float* __restrict__ w_p, const float* __restrict__ b_p,
                float* __restrict__ out)
{
    __shared__ __align__(16) float hcur[64];            // h1@[0..19], h2@[32..51]
    __shared__ __align__(16) float h2out[CHUNK * HIDN];

    const int lane = threadIdx.x;
    const int blk  = blockIdx.x;
    const int t0   = blk * CHUNK;
    const int start = (t0 >= WARM) ? (t0 - WARM) : 0;
    const int endt  = t0 + CHUNK;

    hcur[lane] = 0.0f;

    const int grp  = lane / 20;
    const int k    = lane - grp * 20;
    const int krow = (grp < 3) ? k : 0;
    const float scale = (grp < 3) ? 1.0f : 0.0f;
    const float* wbase = (grp == 1) ? w_ih2 : ((grp == 2) ? w_hh2 : w_hh1);

    DECLW2(0) DECLW2(1) DECLW2(2) DECLW2(3)
    LOADW2(0) LOADW2(1) LOADW2(2) LOADW2(3)

    const float* vbase = (lane < 40) ? hcur : (hcur + 32);
    const bool  isl2   = (lane >= 20 && lane < 40);
    const float m2     = isl2 ? 1.0f : 0.0f;
    const float m1     = (grp == 0) ? 1.0f : 0.0f;   // only L1 lanes add xg
    const int   h2col  = lane - 20;
    const int   hslot  = (lane < 20) ? lane : (32 + h2col);
    const int   shsrc  = (lane + 20) & 63;

    // xg stream, depth-1 register prefetch (lanes>=20 duplicate lane-k rows:
    // same cache lines, no extra HBM traffic; proj output is L3-hot anyway)
    float4v xg_use = xg[XGIDX(start)];
    float4v xg_pref;

    __syncthreads();

    float c = 0.0f, h = 0.0f;

    // ---- peeled first step (s == start): h,c zero -> gates are xg/bias only
    {
        float a0 = fmaf(m1, xg_use.x, bq0);
        float a2 = fmaf(m1, xg_use.z, bq2);
        float a3 = fmaf(m1, xg_use.w, bq3);
        float gi = sigf(a0), gg = tanhfst(a2), go = sigf(a3);
        float cn = gi * gg;
        float hn = go * tanhfst(cn);
        c = (lane < 20) ? cn : 0.0f;
        h = (lane < 20) ? hn : 0.0f;
        if (lane < 40) hcur[hslot] = h;   // layer-2 slots stay 0
        __syncthreads();
    }

    xg_pref = xg[XGIDX(start + 1)];

    // ---- main loop: s = start+1 .. endt
    for (int s = start + 1; s <= endt; ++s) {
        xg_use  = xg_pref;                 // vmcnt wait lands here, before compute
        xg_pref = xg[XGIDX(s + 1)];        // in flight across the whole step

        const float4v* vb4 = (const float4v*)vbase;
        float4v v  = vb4[0];
        float4v s0 = wv00 * v, s1 = wv10 * v, s2 = wv20 * v, s3 = wv30 * v;
        v = vb4[1]; s0 += wv01 * v; s1 += wv11 * v; s2 += wv21 * v; s3 += wv31 * v;
        v = vb4[2]; s0 += wv02 * v; s1 += wv12 * v; s2 += wv22 * v; s3 += wv32 * v;
        v = vb4[3]; s0 += wv03 * v; s1 += wv13 * v; s2 += wv23 * v; s3 += wv33 * v;
        v = vb4[4]; s0 += wv04 * v; s1 += wv14 * v; s2 += wv24 * v; s3 += wv34 * v;

        float a0 = hsum4(s0) + fmaf(m1, xg_use.x, bq0);
        float a1 = hsum4(s1) + fmaf(m1, xg_use.y, bq1);
        float a2 = hsum4(s2) + fmaf(m1, xg_use.z, bq2);
        float a3 = hsum4(s3) + fmaf(m1, xg_use.w, bq3);

        // layer-2 combine: lane 20+k += lane 40+k (masked fma)
        a0 = fmaf(m2, __shfl(a0, shsrc, 64), a0);
        a1 = fmaf(m2, __shfl(a1, shsrc, 64), a1);
        a2 = fmaf(m2, __shfl(a2, shsrc, 64), a2);
        a3 = fmaf(m2, __shfl(a3, shsrc, 64), a3);

        float gi = sigf(a0), gf = sigf(a1), gg = tanhfst(a2), go = sigf(a3);
        c = fmaf(gf, c, gi * gg);
        h = go * tanhfst(c);

        if (lane < 40) hcur[hslot] = h;
        if (isl2 && s > t0) h2out[(s - 1 - t0) * HIDN + h2col] = h;

        __syncthreads();
    }

    // ---- projection epilogue: out[t] = w_p . h2[t] + b_p  (one t per lane)
    {
        const float4v* wp4 = (const float4v*)w_p;
        float4v p0 = wp4[0], p1 = wp4[1], p2 = wp4[2], p3 = wp4[3], p4 = wp4[4];
        const float bp = b_p[0];
        for (int tt = lane; tt < CHUNK; tt += 64) {
            const float4v* hr = (const float4v*)(h2out + tt * HIDN);
            float4v s_ = p0 * hr[0];
            s_ += p1 * hr[1]; s_ += p2 * hr[2]; s_ += p3 * hr[3]; s_ += p4 * hr[4];
            out[t0 + tt] = hsum4(s_) + bp;
        }
    }
}

// ============================================================================
// Fallback (previous kernel, verbatim geometry): used only if ws_size is too
// small for the xg workspace. Keeps the round safe against an undersized ws.
// ============================================================================
#define V0CHUNK 128
#define V0WARM 48
#define V0MAXST (V0WARM + V0CHUNK + 1)
#define V0NBLK (T_TOTAL / V0CHUNK)

#define DECLW(q) \
    float4v w0v##q##0, w0v##q##1, w0v##q##2, w0v##q##3, w0v##q##4; \
    float4v w0x##q##0, w0x##q##1; float w0x##q##8; float b0q##q;

#define LOADW(q) { \
    const float4v* wr = (const float4v*)(wbase + ((q) * HIDN + krow) * HIDN); \
    w0v##q##0 = scale * wr[0]; w0v##q##1 = scale * wr[1]; w0v##q##2 = scale * wr[2]; \
    w0v##q##3 = scale * wr[3]; w0v##q##4 = scale * wr[4]; \
    w0x##q##0 = (float4v)0.0f; w0x##q##1 = (float4v)0.0f; w0x##q##8 = 0.0f; \
    if (grp == 0) { \
        const float* r = w_ih1 + ((q) * HIDN + k) * IND; \
        w0x##q##0 = (float4v){r[0], r[1], r[2], r[3]}; \
        w0x##q##1 = (float4v){r[4], r[5], r[6], r[7]}; \
        w0x##q##8 = r[8]; \
    } \
    b0q##q = (grp == 0) ? b1[(q) * HIDN + k] : ((grp == 1) ? b2[(q) * HIDN + k] : 0.0f); \
}

#define GATE(q) ({ \
    float4v s_ = w0v##q##0 * v0; \
    s_ += w0v##q##1 * v1; s_ += w0v##q##2 * v2; \
    s_ += w0v##q##3 * v3; s_ += w0v##q##4 * v4; \
    s_ += w0x##q##0 * xv0; s_ += w0x##q##1 * xv1; \
    hsum4(s_) + fmaf(w0x##q##8, xv8, b0q##q); })

#define GATEX(q) ({ \
    float4v s_ = w0x##q##0 * xv0 + w0x##q##1 * xv1; \
    hsum4(s_) + fmaf(w0x##q##8, xv8, b0q##q); })

__global__ __launch_bounds__(64)
void lstm_scan_v0(const float* __restrict__ x,
                  const float* __restrict__ w_ih1, const float* __restrict__ w_hh1,
                  const float* __restrict__ b1,
                  const float* __restrict__ w_ih2, const float* __restrict__ w_hh2,
                  const float* __restrict__ b2,
                  const float* __restrict__ w_p, const float* __restrict__ b_p,
                  float* __restrict__ out)
{
    __shared__ __align__(16) float xbuf[V0MAXST * 12];
    __shared__ __align__(16) float hcur[64];
    __shared__ __align__(16) float h2out[V0CHUNK * HIDN];

    const int lane = threadIdx.x;
    const int blk  = blockIdx.x;
    const int t0   = blk * V0CHUNK;
    const int start = (t0 >= V0WARM) ? (t0 - V0WARM) : 0;
    const int endt  = t0 + V0CHUNK;
    const int nst   = endt - start + 1;

    for (int idx = lane; idx < nst * IND; idx += 64) {
        int stp = idx / IND, d = idx - stp * IND;
        int gt = start + stp; if (gt > T_TOTAL - 1) gt = T_TOTAL - 1;
        xbuf[stp * 12 + d] = x[gt * IND + d];
    }
    hcur[lane] = 0.0f;

    const int grp  = lane / 20;
    const int k    = lane - grp * 20;
    const int krow = (grp < 3) ? k : 0;
    const float scale = (grp < 3) ? 1.0f : 0.0f;
    const float* wbase = (grp == 1) ? w_ih2 : ((grp == 2) ? w_hh2 : w_hh1);

    DECLW(0) DECLW(1) DECLW(2) DECLW(3)
    LOADW(0) LOADW(1) LOADW(2) LOADW(3)

    const float* vbase = (lane < 40) ? hcur : (hcur + 32);
    const bool  isl2   = (lane >= 20 && lane < 40);
    const float m2     = isl2 ? 1.0f : 0.0f;
    const int   h2col  = lane - 20;
    const int   hslot  = (lane < 20) ? lane : (32 + h2col);
    const int   shsrc  = (lane + 20) & 63;

    __syncthreads();

    float c = 0.0f, h = 0.0f;

    {
        const float* xr = &xbuf[0];
        float4v xv0 = *(const float4v*)xr, xv1 = *(const float4v*)(xr + 4);
        float xv8 = xr[8];
        float a0 = GATEX(0), a1 = GATEX(1), a2 = GATEX(2), a3 = GATEX(3);
        float gi = sigf(a0), gg = tanhfst(a2), go = sigf(a3);
        (void)a1;
        float cn = gi * gg;
        float hn = go * tanhfst(cn);
        c = (lane < 20) ? cn : 0.0f;
        h = (lane < 20) ? hn : 0.0f;
        if (lane < 40) hcur[hslot] = h;
        __syncthreads();
    }

    for (int s = start + 1; s <= endt; ++s) {
        const float4v* vb4 = (const float4v*)vbase;
        float4v v0 = vb4[0], v1 = vb4[1], v2 = vb4[2], v3 = vb4[3], v4 = vb4[4];

        const float* xr = &xbuf[(s - start) * 12];
        float4v xv0 = *(const float4v*)xr, xv1 = *(const float4v*)(xr + 4);
        float xv8 = xr[8];

        float a0 = GATE(0), a1 = GATE(1), a2 = GATE(2), a3 = GATE(3);

        a0 = fmaf(m2, __shfl(a0, shsrc, 64), a0);
        a1 = fmaf(m2, __shfl(a1, shsrc, 64), a1);
        a2 = fmaf(m2, __shfl(a2, shsrc, 64), a2);
        a3 = fmaf(m2, __shfl(a3, shsrc, 64), a3);

        float gi = sigf(a0), gf = sigf(a1), gg = tanhfst(a2), go = sigf(a3);
        c = fmaf(gf, c, gi * gg);
        h = go * tanhfst(c);

        if (lane < 40) hcur[hslot] = h;
        if (isl2 && s > t0) h2out[(s - 1 - t0) * HIDN + h2col] = h;

        __syncthreads();
    }

    {
        const float4v* wp4 = (const float4v*)w_p;
        float4v p0 = wp4[0], p1 = wp4[1], p2 = wp4[2], p3 = wp4[3], p4 = wp4[4];
        const float bp = b_p[0];
        for (int tt = lane; tt < V0CHUNK; tt += 64) {
            const float4v* hr = (const float4v*)(h2out + tt * HIDN);
            float4v s_ = p0 * hr[0];
            s_ += p1 * hr[1]; s_ += p2 * hr[2]; s_ += p3 * hr[3]; s_ += p4 * hr[4];
            out[t0 + tt] = hsum4(s_) + bp;
        }
    }
}

extern "C" void kernel_launch(void* const* d_in, const int* in_sizes, int n_in,
                              void* d_out, int out_size, void* d_ws, size_t ws_size,
                              hipStream_t stream) {
    const float* x     = (const float*)d_in[0];
    const float* w_ih1 = (const float*)d_in[1];
    const float* w_hh1 = (const float*)d_in[2];
    const float* b1    = (const float*)d_in[3];
    const float* w_ih2 = (const float*)d_in[4];
    const float* w_hh2 = (const float*)d_in[5];
    const float* b2    = (const float*)d_in[6];
    const float* w_p   = (const float*)d_in[7];
    const float* b_p   = (const float*)d_in[8];
    float* out = (float*)d_out;

    if (ws_size >= XG_BYTES && d_ws != nullptr) {
        float4v* xg = (float4v*)d_ws;
        xproj<<<(T_TOTAL * HIDN) / 256, 256, 0, stream>>>(x, w_ih1, b1, xg);
        lstm_scan2<<<NBLK, 64, 0, stream>>>(xg, w_hh1, w_ih2, w_hh2, b2,
                                            w_p, b_p, out);
    } else {
        // workspace too small for xg: previous-generation fused kernel
        lstm_scan_v0<<<V0NBLK, 64, 0, stream>>>(x, w_ih1, w_hh1, b1,
                                                w_ih2, w_hh2, b2, w_p, b_p, out);
    }
}